// Round 3
// baseline (292.298 us; speedup 1.0000x reference)
//
#include <hip/hip_runtime.h>

// Volume renderer, LDS-staged version.
// R1 showed stride-12/36 scalar global loads tax the L1/TA pipe ~6x (each
// instruction touches 12-36 cache lines). Fix: block-cooperative float4
// global<->LDS staging (1 touch per 64B line), compute phase reads LDS at
// stride 3/9 (coprime with 32 banks -> 2 lanes/bank = conflict-free).
// One wave per ray, lane l owns contiguous samples {3l,3l+1,3l+2}; exclusive
// cumprod = in-lane products + one 6-step wave product scan.

#define NRAYS 65536
#define L 192
#define RPB 4                 // rays (waves) per 256-thread block
#define BORDER_W 1e10f
#define EPS_F 1e-10f

__device__ __forceinline__ float fast_sigmoid(float x) {
    return __builtin_amdgcn_rcpf(1.0f + __expf(-x));
}

__global__ __launch_bounds__(256) void vol_render_kernel(
    const float* __restrict__ depth,   // [N, 192]
    const float* __restrict__ rgb,     // [N, 192, 3]
    const float* __restrict__ sigma,   // [N, 192]
    float* __restrict__ out)           // color N*3 | depth N | acc N | weights N*192
{
    __shared__ float4 s4d[RPB * 48 + 1];   // depth (+4-float pad for d[b+3] read)
    __shared__ float4 s4s[RPB * 48];       // sigma
    __shared__ float4 s4r[RPB * 144];      // rgb
    __shared__ float4 s4w[RPB * 48];       // weights staging

    const int tid  = threadIdx.x;
    const int lane = tid & 63;
    const int wv   = tid >> 6;
    const int ray0 = blockIdx.x * RPB;
    const int ray  = ray0 + wv;

    // ---- cooperative float4 staging (fully coalesced, minimal line-touches)
    const float4* gd = (const float4*)(depth + (size_t)ray0 * L);       // 192 f4
    const float4* gs = (const float4*)(sigma + (size_t)ray0 * L);       // 192 f4
    const float4* gr = (const float4*)(rgb   + (size_t)ray0 * (L * 3)); // 576 f4

    if (tid < RPB * 48) { s4d[tid] = gd[tid]; s4s[tid] = gs[tid]; }
#pragma unroll
    for (int i = tid; i < RPB * 144; i += 256) s4r[i] = gr[i];
    __syncthreads();

    // ---- per-wave compute from LDS
    const float* ld = (const float*)s4d + wv * L;
    const float* ls = (const float*)s4s + wv * L;
    const float* lr = (const float*)s4r + wv * (L * 3) + lane * 9;
    float*       lw = (float*)s4w + wv * L;
    const int b = lane * 3;

    float d0 = ld[b], d1 = ld[b + 1], d2 = ld[b + 2], d3 = ld[b + 3];
    float s0 = ls[b], s1 = ls[b + 1], s2 = ls[b + 2];

    float delta0 = d1 - d0;
    float delta1 = d2 - d1;
    float delta2 = (lane == 63) ? BORDER_W : (d3 - d2);   // sample 191 = border

    float e0 = __expf(-(s0 > 0.f ? s0 : 0.f) * delta0);
    float e1 = __expf(-(s1 > 0.f ? s1 : 0.f) * delta1);
    float e2 = __expf(-(s2 > 0.f ? s2 : 0.f) * delta2);
    float surv0 = e0 + EPS_F, surv1 = e1 + EPS_F, surv2 = e2 + EPS_F;

    // in-lane prefix products, then wave-wide inclusive product scan
    float p01  = surv0 * surv1;
    float p012 = p01 * surv2;
    float p = p012;
#pragma unroll
    for (int off = 1; off < 64; off <<= 1) {
        float t = __shfl_up(p, off, 64);
        if (lane >= off) p *= t;
    }
    float excl = __shfl_up(p, 1, 64);
    if (lane == 0) excl = 1.0f;

    float T0 = excl;
    float T1 = excl * surv0;
    float T2 = excl * p01;
    float w0 = (1.0f - e0) * T0;
    float w1 = (1.0f - e1) * T1;
    float w2 = (1.0f - e2) * T2;

    lw[b] = w0; lw[b + 1] = w1; lw[b + 2] = w2;   // stage weights in LDS

    // rgb accumulation from LDS (stride-9: conflict-free)
    float col0 = w0 * fast_sigmoid(lr[0]) + w1 * fast_sigmoid(lr[3]) + w2 * fast_sigmoid(lr[6]);
    float col1 = w0 * fast_sigmoid(lr[1]) + w1 * fast_sigmoid(lr[4]) + w2 * fast_sigmoid(lr[7]);
    float col2 = w0 * fast_sigmoid(lr[2]) + w1 * fast_sigmoid(lr[5]) + w2 * fast_sigmoid(lr[8]);
    float dep  = w0 * d0 + w1 * d1 + w2 * d2;
    float acc  = w0 + w1 + w2;

    // wave-wide reduction of the 5 partial sums
#pragma unroll
    for (int off = 32; off >= 1; off >>= 1) {
        col0 += __shfl_down(col0, off, 64);
        col1 += __shfl_down(col1, off, 64);
        col2 += __shfl_down(col2, off, 64);
        dep  += __shfl_down(dep,  off, 64);
        acc  += __shfl_down(acc,  off, 64);
    }
    if (lane == 0) {
        out[(size_t)ray * 3 + 0] = col0;
        out[(size_t)ray * 3 + 1] = col1;
        out[(size_t)ray * 3 + 2] = col2;
        out[(size_t)NRAYS * 3 + ray] = dep;
        out[(size_t)NRAYS * 4 + ray] = acc;
    }

    // ---- cooperative float4 weight store
    __syncthreads();
    float4* gw = (float4*)(out + (size_t)NRAYS * 5);
    if (tid < RPB * 48) gw[(size_t)blockIdx.x * (RPB * 48) + tid] = s4w[tid];
}

extern "C" void kernel_launch(void* const* d_in, const int* in_sizes, int n_in,
                              void* d_out, int out_size, void* d_ws, size_t ws_size,
                              hipStream_t stream) {
    const float* depth = (const float*)d_in[0];
    const float* rgb   = (const float*)d_in[1];
    const float* sigma = (const float*)d_in[2];
    float* out = (float*)d_out;

    dim3 grid(NRAYS / RPB);
    dim3 block(256);
    vol_render_kernel<<<grid, block, 0, stream>>>(depth, rgb, sigma, out);
}